// Round 3
// baseline (52.745 us; speedup 1.0000x reference)
//
#include <hip/hip_runtime.h>
#include <hip/hip_bf16.h>
#include <stdint.h>

// Only the LAST (seg_len=2048, dil=4) group survives in the reference.
// 2 segments x 16 heads; seg0 keys n=0,4,..,4092 (1024), seg1 keys
// n=2048,..,4092 (512). Non-causal attention, shared valid-key set.

#define NH   16
#define HD   64
#define KMAX 1024

typedef __attribute__((ext_vector_type(8))) short s16x8;
typedef __attribute__((ext_vector_type(4))) short s16x4;
typedef __attribute__((ext_vector_type(4))) float f32x4;

__device__ __forceinline__ ushort f2bf(float x) {
    union { float f; unsigned u; } c; c.f = x;
    unsigned u = c.u;
    u += 0x7fffu + ((u >> 16) & 1u);   // RTNE
    return (ushort)(u >> 16);
}

__device__ __forceinline__ float fexp2(float x) {
#if __has_builtin(__builtin_amdgcn_exp2f)
    return __builtin_amdgcn_exp2f(x);
#else
    return exp2f(x);
#endif
}

__device__ __forceinline__ void async_load16(const ushort* g, ushort* l) {
    __builtin_amdgcn_global_load_lds(
        (const __attribute__((address_space(1))) void*)g,
        (__attribute__((address_space(3))) void*)l, 16, 0, 0);
}

// ---------- prep: gather K/V at dilated positions -> bf16; V stored transposed
__global__ __launch_bounds__(256) void prep_kernel(
    const float* __restrict__ kin, const float* __restrict__ vin,
    ushort* __restrict__ Kb, ushort* __restrict__ Vt)
{
    int bid = blockIdx.x;
    int seg = bid >> 8;
    int h   = (bid >> 4) & 15;
    int ib  = bid & 15;
    int Kv  = seg ? 512 : 1024;
    int i0  = ib * 64;
    if (i0 >= Kv) return;

    int t  = threadIdx.x;
    int il = t >> 2;            // local key row 0..63
    int d0 = (t & 3) * 16;
    int i  = i0 + il;
    int pos = seg * 2048 + i * 4;

    const float* ks = kin + (size_t)pos * (NH*HD) + h * HD + d0;
    const float* vs = vin + (size_t)pos * (NH*HD) + h * HD + d0;

    __attribute__((aligned(16))) ushort kb[16];
    __attribute__((aligned(16))) ushort vb[16];
    #pragma unroll
    for (int j = 0; j < 4; ++j) {
        float4 a = ((const float4*)ks)[j];
        float4 b = ((const float4*)vs)[j];
        kb[j*4+0]=f2bf(a.x); kb[j*4+1]=f2bf(a.y); kb[j*4+2]=f2bf(a.z); kb[j*4+3]=f2bf(a.w);
        vb[j*4+0]=f2bf(b.x); vb[j*4+1]=f2bf(b.y); vb[j*4+2]=f2bf(b.z); vb[j*4+3]=f2bf(b.w);
    }
    size_t kdst = ((size_t)(seg*NH + h) * KMAX + i) * HD + d0;
    ((uint4*)(Kb + kdst))[0] = *(const uint4*)&kb[0];
    ((uint4*)(Kb + kdst))[1] = *(const uint4*)&kb[8];

    __shared__ ushort vl[64 * 72];
    #pragma unroll
    for (int j = 0; j < 16; ++j) vl[il * 72 + d0 + j] = vb[j];
    __syncthreads();

    int d  = t >> 2;
    int ic = (t & 3) * 16;
    __attribute__((aligned(16))) ushort ob[16];
    #pragma unroll
    for (int j = 0; j < 16; ++j) ob[j] = vl[(ic + j) * 72 + d];
    size_t vdst = ((size_t)(seg*NH + h) * HD + d) * KMAX + i0 + ic;
    ((uint4*)(Vt + vdst))[0] = *(const uint4*)&ob[0];
    ((uint4*)(Vt + vdst))[1] = *(const uint4*)&ob[8];
}

// ---------- flash attention: swapped-operand MFMA, in-register softmax,
// 3-buffer LDS pipeline with counted vmcnt + raw s_barrier (T3/T4 minimum).
__global__ __launch_bounds__(256, 4) void attn_kernel(
    const float* __restrict__ qin, const ushort* __restrict__ Kb,
    const ushort* __restrict__ Vt, float* __restrict__ outp)
{
    int bid = blockIdx.x;
    int sh  = bid & 31;          // low bits -> same (seg,h) clusters on one XCD
    int qb  = bid >> 5;
    int seg = sh >> 4;
    int h   = sh & 15;
    int NT  = seg ? 8 : 16;      // key tiles of 64

    int tid  = threadIdx.x;
    int w    = tid >> 6;
    int lane = tid & 63;
    int r15  = lane & 15;
    int g    = lane >> 4;
    int rsw  = r15 & 7;

    // 3 x [K|V] x [64 rows x 64 elems], rows 128B, 16B-chunk XOR swizzle. 48KB.
    __shared__ __attribute__((aligned(16))) ushort smem[3][2][64*64];

    // ---- Q B-fragments; scale folds 1/sqrt(64) * log2(e) -> softmax uses exp2
    const float QSC = 0.125f * 1.4426950408889634f;
    s16x8 qa0, qa1;
    int qrow = seg*2048 + qb*64 + w*16 + r15;
    {
        const float* qs = qin + (size_t)qrow * (NH*HD) + h*HD + g*8;
        float4 a = ((const float4*)qs)[0];
        float4 b = ((const float4*)qs)[1];
        qa0[0]=(short)f2bf(a.x*QSC); qa0[1]=(short)f2bf(a.y*QSC);
        qa0[2]=(short)f2bf(a.z*QSC); qa0[3]=(short)f2bf(a.w*QSC);
        qa0[4]=(short)f2bf(b.x*QSC); qa0[5]=(short)f2bf(b.y*QSC);
        qa0[6]=(short)f2bf(b.z*QSC); qa0[7]=(short)f2bf(b.w*QSC);
        const float* qs1 = qs + 32;
        float4 c = ((const float4*)qs1)[0];
        float4 d = ((const float4*)qs1)[1];
        qa1[0]=(short)f2bf(c.x*QSC); qa1[1]=(short)f2bf(c.y*QSC);
        qa1[2]=(short)f2bf(c.z*QSC); qa1[3]=(short)f2bf(c.w*QSC);
        qa1[4]=(short)f2bf(d.x*QSC); qa1[5]=(short)f2bf(d.y*QSC);
        qa1[6]=(short)f2bf(d.z*QSC); qa1[7]=(short)f2bf(d.w*QSC);
    }

    // ---- staging setup: waves 0-1 stage K, waves 2-3 stage V^T (4 loads/wave/tile)
    const ushort* KbH = Kb + (size_t)(seg*NH + h) * KMAX * HD;
    const ushort* VtH = Vt + (size_t)(seg*NH + h) * HD * KMAX;
    int sub = lane >> 3;
    int csw = (lane & 7) ^ sub;          // inverse-swizzled source 16B-chunk
    bool isK = (w < 2);
    int kvsel = isK ? 0 : 1;
    size_t stride = isK ? (size_t)(64*HD) : (size_t)64;  // elems per tile step
    const ushort* gsrc[4];
    {
        int clb = (w & 1) * 4;
        #pragma unroll
        for (int cc = 0; cc < 4; ++cc) {
            int cl   = clb + cc;         // chunk 0..7 within K or V half
            int rowl = cl*8 + sub;       // row 0..63
            gsrc[cc] = isK ? (KbH + (size_t)rowl*HD   + csw*8)
                           : (VtH + (size_t)rowl*KMAX + csw*8);
        }
    }
    ushort* sb0 = &smem[0][kvsel][(w & 1) * 2048];
    ushort* sb1 = &smem[1][kvsel][(w & 1) * 2048];
    ushort* sb2 = &smem[2][kvsel][(w & 1) * 2048];

    auto stage = [&](ushort* base, int t) {
        size_t off = (size_t)t * stride;
        #pragma unroll
        for (int cc = 0; cc < 4; ++cc) async_load16(gsrc[cc] + off, base + cc*512);
    };

    f32x4 O[4] = {{0,0,0,0},{0,0,0,0},{0,0,0,0},{0,0,0,0}};  // O^T[d=dt*16+4g+r][q=r15]
    float m = -3e38f, l = 0.f;

    auto compute = [&](const ushort* kbuf, const ushort* vbuf) {
        // QK^T swapped: lane holds S[q=r15][k=16t+4g+r] in log2 units
        f32x4 st[4];
        #pragma unroll
        for (int tt = 0; tt < 4; ++tt) {
            const ushort* kr = kbuf + (tt*16 + r15) * HD;
            s16x8 a0 = *(const s16x8*)(kr + (( g      ^ rsw) << 3));
            s16x8 a1 = *(const s16x8*)(kr + (((g + 4) ^ rsw) << 3));
            f32x4 z = {0.f,0.f,0.f,0.f};
            z      = __builtin_amdgcn_mfma_f32_16x16x32_bf16(a0, qa0, z, 0,0,0);
            st[tt] = __builtin_amdgcn_mfma_f32_16x16x32_bf16(a1, qa1, z, 0,0,0);
        }
        float m0 = fmaxf(fmaxf(st[0][0], st[0][1]), fmaxf(st[0][2], st[0][3]));
        float m1 = fmaxf(fmaxf(st[1][0], st[1][1]), fmaxf(st[1][2], st[1][3]));
        float m2 = fmaxf(fmaxf(st[2][0], st[2][1]), fmaxf(st[2][2], st[2][3]));
        float m3 = fmaxf(fmaxf(st[3][0], st[3][1]), fmaxf(st[3][2], st[3][3]));
        float mt = fmaxf(fmaxf(m0, m1), fmaxf(m2, m3));
        mt = fmaxf(mt, __shfl_xor(mt, 16));
        mt = fmaxf(mt, __shfl_xor(mt, 32));
        // defer-max (T13), threshold in log2 units (p bounded by 2^11)
        if (!__all(mt <= m + 11.0f)) {
            float mn = fmaxf(m, mt);
            float al = fexp2(m - mn);
            m = mn;
            l *= al;
            #pragma unroll
            for (int dt = 0; dt < 4; ++dt) {
                f32x4 o = O[dt];
                o[0]*=al; o[1]*=al; o[2]*=al; o[3]*=al;
                O[dt] = o;
            }
        }
        // P = exp2(S - m); per-lane partial row-sum (reduced once in epilogue)
        float rs = 0.f;
        s16x4 pf[4];
        #pragma unroll
        for (int tt = 0; tt < 4; ++tt) {
            float p0 = fexp2(st[tt][0] - m);
            float p1 = fexp2(st[tt][1] - m);
            float p2 = fexp2(st[tt][2] - m);
            float p3 = fexp2(st[tt][3] - m);
            rs += (p0 + p1) + (p2 + p3);
            s16x4 pv;
            pv[0]=(short)f2bf(p0); pv[1]=(short)f2bf(p1);
            pv[2]=(short)f2bf(p2); pv[3]=(short)f2bf(p3);
            pf[tt] = pv;
        }
        l += rs;
        // PV swapped: O^T += V^T * P^T via 16x16x16 bf16 MFMA (P already B-frag)
        #pragma unroll
        for (int dt = 0; dt < 4; ++dt) {
            const ushort* vr = vbuf + (dt*16 + r15) * HD;
            #pragma unroll
            for (int tt = 0; tt < 4; ++tt) {
                int c = 2*tt + (g >> 1);
                s16x4 vf = *(const s16x4*)(vr + ((c ^ rsw) << 3) + 4*(g & 1));
                O[dt] = __builtin_amdgcn_mfma_f32_16x16x16bf16_1k(vf, pf[tt], O[dt], 0,0,0);
            }
        }
    };

    // ---- pipeline: 3 buffers, counted vmcnt, raw barriers; loads never drain to 0
    stage(sb0, 0);
    stage(sb1, 1);
    asm volatile("s_waitcnt vmcnt(4)" ::: "memory");   // tile0's 4 done, tile1's in flight
    __builtin_amdgcn_s_barrier();

#define ITER(B, NXT)                                                          \
    {                                                                         \
        if (t + 2 < NT) stage(NXT, t + 2);                                    \
        compute(&smem[B][0][0], &smem[B][1][0]);                              \
        asm volatile("s_waitcnt lgkmcnt(0)" ::: "memory");                    \
        if (t + 1 < NT) {                                                     \
            if (t + 2 < NT) asm volatile("s_waitcnt vmcnt(4)" ::: "memory");  \
            else            asm volatile("s_waitcnt vmcnt(0)" ::: "memory");  \
            __builtin_amdgcn_s_barrier();                                     \
        }                                                                     \
    }

    int t = 0;
    for (;;) {
        ITER(0, sb2); if (++t == NT) break;
        ITER(1, sb0); if (++t == NT) break;
        ITER(2, sb1); if (++t == NT) break;
    }
#undef ITER

    // ---- epilogue: reduce per-lane l across the 4 g-groups, normalize, store
    l += __shfl_xor(l, 16);
    l += __shfl_xor(l, 32);
    float invl = 1.0f / l;
    float* ob = outp + (size_t)qrow * (NH*HD) + h*HD + g*4;
    #pragma unroll
    for (int dt = 0; dt < 4; ++dt) {
        float4 o4 = { O[dt][0]*invl, O[dt][1]*invl, O[dt][2]*invl, O[dt][3]*invl };
        *(float4*)(ob + dt*16) = o4;
    }
}

extern "C" void kernel_launch(void* const* d_in, const int* in_sizes, int n_in,
                              void* d_out, int out_size, void* d_ws, size_t ws_size,
                              hipStream_t stream) {
    const float* q = (const float*)d_in[0];
    const float* k = (const float*)d_in[1];
    const float* v = (const float*)d_in[2];
    float* out = (float*)d_out;

    ushort* Kb = (ushort*)d_ws;                          // [2][16][1024][64] bf16
    ushort* Vt = Kb + (size_t)2 * NH * KMAX * HD;        // [2][16][64][1024] bf16

    prep_kernel<<<512, 256, 0, stream>>>(k, v, Kb, Vt);
    attn_kernel<<<1024, 256, 0, stream>>>(q, Kb, Vt, out);
}

// Round 4
// 42.121 us; speedup vs baseline: 1.2522x; 1.2522x over previous
//
#include <hip/hip_runtime.h>
#include <hip/hip_bf16.h>
#include <stdint.h>

// Only the LAST (seg_len=2048, dil=4) group survives in the reference.
// 2 segments x 16 heads; seg0 keys n=0,4,..,4092 (1024), seg1 keys
// n=2048,..,4092 (512). Non-causal attention, shared valid-key set.

#define NH   16
#define HD   64
#define KMAX 1024

typedef __attribute__((ext_vector_type(8))) short s16x8;
typedef __attribute__((ext_vector_type(4))) short s16x4;
typedef __attribute__((ext_vector_type(4))) float f32x4;

__device__ __forceinline__ ushort f2bf(float x) {
    union { float f; unsigned u; } c; c.f = x;
    unsigned u = c.u;
    u += 0x7fffu + ((u >> 16) & 1u);   // RTNE
    return (ushort)(u >> 16);
}

__device__ __forceinline__ float fexp2(float x) {
#if __has_builtin(__builtin_amdgcn_exp2f)
    return __builtin_amdgcn_exp2f(x);
#else
    return exp2f(x);
#endif
}

__device__ __forceinline__ void async_load16(const ushort* g, ushort* l) {
    __builtin_amdgcn_global_load_lds(
        (const __attribute__((address_space(1))) void*)g,
        (__attribute__((address_space(3))) void*)l, 16, 0, 0);
}

// ---------- prep: gather K/V at dilated positions -> bf16; V stored transposed
__global__ __launch_bounds__(256) void prep_kernel(
    const float* __restrict__ kin, const float* __restrict__ vin,
    ushort* __restrict__ Kb, ushort* __restrict__ Vt)
{
    int bid = blockIdx.x;
    int seg = bid >> 8;
    int h   = (bid >> 4) & 15;
    int ib  = bid & 15;
    int Kv  = seg ? 512 : 1024;
    int i0  = ib * 64;
    if (i0 >= Kv) return;

    int t  = threadIdx.x;
    int il = t >> 2;            // local key row 0..63
    int d0 = (t & 3) * 16;
    int i  = i0 + il;
    int pos = seg * 2048 + i * 4;

    const float* ks = kin + (size_t)pos * (NH*HD) + h * HD + d0;
    const float* vs = vin + (size_t)pos * (NH*HD) + h * HD + d0;

    __attribute__((aligned(16))) ushort kb[16];
    __attribute__((aligned(16))) ushort vb[16];
    #pragma unroll
    for (int j = 0; j < 4; ++j) {
        float4 a = ((const float4*)ks)[j];
        float4 b = ((const float4*)vs)[j];
        kb[j*4+0]=f2bf(a.x); kb[j*4+1]=f2bf(a.y); kb[j*4+2]=f2bf(a.z); kb[j*4+3]=f2bf(a.w);
        vb[j*4+0]=f2bf(b.x); vb[j*4+1]=f2bf(b.y); vb[j*4+2]=f2bf(b.z); vb[j*4+3]=f2bf(b.w);
    }
    size_t kdst = ((size_t)(seg*NH + h) * KMAX + i) * HD + d0;
    ((uint4*)(Kb + kdst))[0] = *(const uint4*)&kb[0];
    ((uint4*)(Kb + kdst))[1] = *(const uint4*)&kb[8];

    __shared__ ushort vl[64 * 72];
    #pragma unroll
    for (int j = 0; j < 16; ++j) vl[il * 72 + d0 + j] = vb[j];
    __syncthreads();

    int d  = t >> 2;
    int ic = (t & 3) * 16;
    __attribute__((aligned(16))) ushort ob[16];
    #pragma unroll
    for (int j = 0; j < 16; ++j) ob[j] = vl[(ic + j) * 72 + d];
    size_t vdst = ((size_t)(seg*NH + h) * HD + d) * KMAX + i0 + ic;
    ((uint4*)(Vt + vdst))[0] = *(const uint4*)&ob[0];
    ((uint4*)(Vt + vdst))[1] = *(const uint4*)&ob[8];
}

// ---------- flash attention: 32 queries/wave (2 q-groups), swapped-operand
// MFMA, in-register softmax, 3-buffer counted-vmcnt pipeline.
__global__ __launch_bounds__(256, 2) void attn_kernel(
    const float* __restrict__ qin, const ushort* __restrict__ Kb,
    const ushort* __restrict__ Vt, float* __restrict__ outp)
{
    int bid = blockIdx.x;        // 0..255 seg0 (long blocks first), 256..511 seg1
    int seg = bid >> 8;
    int h   = (bid >> 4) & 15;
    int qb  = bid & 15;
    int NT  = seg ? 8 : 16;      // key tiles of 64

    int tid  = threadIdx.x;
    int w    = tid >> 6;
    int lane = tid & 63;
    int r15  = lane & 15;
    int g    = lane >> 4;
    int rsw  = r15 & 7;

    // 3 x [K|V] x [64 rows x 64 elems], rows 128B, 16B-chunk XOR swizzle. 48KB.
    __shared__ __attribute__((aligned(16))) ushort smem[3][2][64*64];

    // ---- Q B-fragments for 2 q-groups; scale folds 1/8 * log2(e) -> exp2 softmax
    const float QSC = 0.125f * 1.4426950408889634f;
    s16x8 qa[2][2];
    int qrow0 = seg*2048 + qb*128 + w*32 + r15;   // q-group 0 row; group 1 = +16
    #pragma unroll
    for (int qg = 0; qg < 2; ++qg) {
        const float* qs = qin + (size_t)(qrow0 + qg*16) * (NH*HD) + h*HD + g*8;
        float4 a = ((const float4*)qs)[0];
        float4 b = ((const float4*)qs)[1];
        s16x8 r0;
        r0[0]=(short)f2bf(a.x*QSC); r0[1]=(short)f2bf(a.y*QSC);
        r0[2]=(short)f2bf(a.z*QSC); r0[3]=(short)f2bf(a.w*QSC);
        r0[4]=(short)f2bf(b.x*QSC); r0[5]=(short)f2bf(b.y*QSC);
        r0[6]=(short)f2bf(b.z*QSC); r0[7]=(short)f2bf(b.w*QSC);
        qa[qg][0] = r0;
        const float* qs1 = qs + 32;
        float4 c = ((const float4*)qs1)[0];
        float4 d = ((const float4*)qs1)[1];
        s16x8 r1;
        r1[0]=(short)f2bf(c.x*QSC); r1[1]=(short)f2bf(c.y*QSC);
        r1[2]=(short)f2bf(c.z*QSC); r1[3]=(short)f2bf(c.w*QSC);
        r1[4]=(short)f2bf(d.x*QSC); r1[5]=(short)f2bf(d.y*QSC);
        r1[6]=(short)f2bf(d.z*QSC); r1[7]=(short)f2bf(d.w*QSC);
        qa[qg][1] = r1;
    }

    // ---- staging: waves 0-1 stage K, waves 2-3 stage V^T (4 loads/wave/tile)
    const ushort* KbH = Kb + (size_t)(seg*NH + h) * KMAX * HD;
    const ushort* VtH = Vt + (size_t)(seg*NH + h) * HD * KMAX;
    int sub = lane >> 3;
    int csw = (lane & 7) ^ sub;          // inverse-swizzled source 16B-chunk
    bool isK = (w < 2);
    int kvsel = isK ? 0 : 1;
    size_t stride = isK ? (size_t)(64*HD) : (size_t)64;
    const ushort* gsrc[4];
    {
        int clb = (w & 1) * 4;
        #pragma unroll
        for (int cc = 0; cc < 4; ++cc) {
            int cl   = clb + cc;
            int rowl = cl*8 + sub;
            gsrc[cc] = isK ? (KbH + (size_t)rowl*HD   + csw*8)
                           : (VtH + (size_t)rowl*KMAX + csw*8);
        }
    }
    ushort* sb0 = &smem[0][kvsel][(w & 1) * 2048];
    ushort* sb1 = &smem[1][kvsel][(w & 1) * 2048];
    ushort* sb2 = &smem[2][kvsel][(w & 1) * 2048];

    auto stage = [&](ushort* base, int t) {
        size_t off = (size_t)t * stride;
        #pragma unroll
        for (int cc = 0; cc < 4; ++cc) async_load16(gsrc[cc] + off, base + cc*512);
    };

    f32x4 O[2][4] = {{{0,0,0,0},{0,0,0,0},{0,0,0,0},{0,0,0,0}},
                     {{0,0,0,0},{0,0,0,0},{0,0,0,0},{0,0,0,0}}};
    float m[2] = {-3e38f, -3e38f};
    float l[2] = {0.f, 0.f};

    auto compute = [&](const ushort* kbuf, const ushort* vbuf) {
        // QK^T swapped: lane holds S[q=r15 (per group)][k=16tt+4g+r], log2 units
        f32x4 st[2][4];
        __builtin_amdgcn_s_setprio(1);
        #pragma unroll
        for (int tt = 0; tt < 4; ++tt) {
            const ushort* kr = kbuf + (tt*16 + r15) * HD;
            s16x8 a0 = *(const s16x8*)(kr + (( g      ^ rsw) << 3));
            s16x8 a1 = *(const s16x8*)(kr + (((g + 4) ^ rsw) << 3));
            f32x4 z0 = {0.f,0.f,0.f,0.f};
            z0         = __builtin_amdgcn_mfma_f32_16x16x32_bf16(a0, qa[0][0], z0, 0,0,0);
            st[0][tt]  = __builtin_amdgcn_mfma_f32_16x16x32_bf16(a1, qa[0][1], z0, 0,0,0);
            f32x4 z1 = {0.f,0.f,0.f,0.f};
            z1         = __builtin_amdgcn_mfma_f32_16x16x32_bf16(a0, qa[1][0], z1, 0,0,0);
            st[1][tt]  = __builtin_amdgcn_mfma_f32_16x16x32_bf16(a1, qa[1][1], z1, 0,0,0);
        }
        __builtin_amdgcn_s_setprio(0);

        // row max per q-group
        float mt[2];
        #pragma unroll
        for (int qg = 0; qg < 2; ++qg) {
            float m0 = fmaxf(fmaxf(st[qg][0][0], st[qg][0][1]), fmaxf(st[qg][0][2], st[qg][0][3]));
            float m1 = fmaxf(fmaxf(st[qg][1][0], st[qg][1][1]), fmaxf(st[qg][1][2], st[qg][1][3]));
            float m2 = fmaxf(fmaxf(st[qg][2][0], st[qg][2][1]), fmaxf(st[qg][2][2], st[qg][2][3]));
            float m3 = fmaxf(fmaxf(st[qg][3][0], st[qg][3][1]), fmaxf(st[qg][3][2], st[qg][3][3]));
            float v = fmaxf(fmaxf(m0, m1), fmaxf(m2, m3));
            v = fmaxf(v, __shfl_xor(v, 16));
            v = fmaxf(v, __shfl_xor(v, 32));
            mt[qg] = v;
        }
        // defer-max (T13), log2 units (p bounded by 2^11)
        if (!__all((mt[0] <= m[0] + 11.0f) && (mt[1] <= m[1] + 11.0f))) {
            #pragma unroll
            for (int qg = 0; qg < 2; ++qg) {
                float mn = fmaxf(m[qg], mt[qg]);
                float al = fexp2(m[qg] - mn);
                m[qg] = mn;
                l[qg] *= al;
                #pragma unroll
                for (int dt = 0; dt < 4; ++dt) {
                    f32x4 o = O[qg][dt];
                    o[0]*=al; o[1]*=al; o[2]*=al; o[3]*=al;
                    O[qg][dt] = o;
                }
            }
        }
        // P = exp2(S - m); per-lane partial row-sums (reduced in epilogue)
        s16x4 pf[2][4];
        #pragma unroll
        for (int qg = 0; qg < 2; ++qg) {
            float rs = 0.f;
            #pragma unroll
            for (int tt = 0; tt < 4; ++tt) {
                float p0 = fexp2(st[qg][tt][0] - m[qg]);
                float p1 = fexp2(st[qg][tt][1] - m[qg]);
                float p2 = fexp2(st[qg][tt][2] - m[qg]);
                float p3 = fexp2(st[qg][tt][3] - m[qg]);
                rs += (p0 + p1) + (p2 + p3);
                s16x4 pv;
                pv[0]=(short)f2bf(p0); pv[1]=(short)f2bf(p1);
                pv[2]=(short)f2bf(p2); pv[3]=(short)f2bf(p3);
                pf[qg][tt] = pv;
            }
            l[qg] += rs;
        }
        // PV swapped: O^T += V^T * P^T (V-frags shared across q-groups)
        __builtin_amdgcn_s_setprio(1);
        #pragma unroll
        for (int dt = 0; dt < 4; ++dt) {
            const ushort* vr = vbuf + (dt*16 + r15) * HD;
            #pragma unroll
            for (int tt = 0; tt < 4; ++tt) {
                int c = 2*tt + (g >> 1);
                s16x4 vf = *(const s16x4*)(vr + ((c ^ rsw) << 3) + 4*(g & 1));
                O[0][dt] = __builtin_amdgcn_mfma_f32_16x16x16bf16_1k(vf, pf[0][tt], O[0][dt], 0,0,0);
                O[1][dt] = __builtin_amdgcn_mfma_f32_16x16x16bf16_1k(vf, pf[1][tt], O[1][dt], 0,0,0);
            }
        }
        __builtin_amdgcn_s_setprio(0);
    };

    // ---- pipeline: 3 buffers, counted vmcnt, raw barriers
    stage(sb0, 0);
    stage(sb1, 1);
    asm volatile("s_waitcnt vmcnt(4)" ::: "memory");
    __builtin_amdgcn_s_barrier();

#define ITER(B, NXT)                                                          \
    {                                                                         \
        if (t + 2 < NT) stage(NXT, t + 2);                                    \
        compute(&smem[B][0][0], &smem[B][1][0]);                              \
        asm volatile("s_waitcnt lgkmcnt(0)" ::: "memory");                    \
        if (t + 1 < NT) {                                                     \
            if (t + 2 < NT) asm volatile("s_waitcnt vmcnt(4)" ::: "memory");  \
            else            asm volatile("s_waitcnt vmcnt(0)" ::: "memory");  \
            __builtin_amdgcn_s_barrier();                                     \
        }                                                                     \
    }

    int t = 0;
    for (;;) {
        ITER(0, sb2); if (++t == NT) break;
        ITER(1, sb0); if (++t == NT) break;
        ITER(2, sb1); if (++t == NT) break;
    }
#undef ITER

    // ---- epilogue: reduce per-lane l across 4 g-groups, normalize, store
    #pragma unroll
    for (int qg = 0; qg < 2; ++qg) {
        float lv = l[qg];
        lv += __shfl_xor(lv, 16);
        lv += __shfl_xor(lv, 32);
        float invl = 1.0f / lv;
        float* ob = outp + (size_t)(qrow0 + qg*16) * (NH*HD) + h*HD + g*4;
        #pragma unroll
        for (int dt = 0; dt < 4; ++dt) {
            float4 o4 = { O[qg][dt][0]*invl, O[qg][dt][1]*invl,
                          O[qg][dt][2]*invl, O[qg][dt][3]*invl };
            *(float4*)(ob + dt*16) = o4;
        }
    }
}

extern "C" void kernel_launch(void* const* d_in, const int* in_sizes, int n_in,
                              void* d_out, int out_size, void* d_ws, size_t ws_size,
                              hipStream_t stream) {
    const float* q = (const float*)d_in[0];
    const float* k = (const float*)d_in[1];
    const float* v = (const float*)d_in[2];
    float* out = (float*)d_out;

    ushort* Kb = (ushort*)d_ws;                          // [2][16][1024][64] bf16
    ushort* Vt = Kb + (size_t)2 * NH * KMAX * HD;        // [2][16][64][1024] bf16

    prep_kernel<<<512, 256, 0, stream>>>(k, v, Kb, Vt);
    attn_kernel<<<512, 256, 0, stream>>>(q, Kb, Vt, out);
}